// Round 16
// baseline (4959.679 us; speedup 1.0000x reference)
//
#include <hip/hip_runtime.h>
#include <hip/hip_bf16.h>
#include <math.h>

// ---- problem dims ----
constexpr int NB   = 32;
constexpr int NS   = 256;
constexpr int NLC  = 16;
constexpr int NWD  = 256;
constexpr int NCD  = 124;
constexpr int NCO  = 32;
constexpr int NPOS = 36;
constexpr int NENR = 7;
constexpr int NH   = 512;
constexpr int NT   = 18;
constexpr int NIN0 = 331;
constexpr int NIN0P= 352;    // padded to x32
constexpr int NIN1 = 1024;
constexpr int NBS  = NB*NS;  // 8192
constexpr int NG4  = 4*NH;   // 2048
constexpr int NGS  = 4096;   // fused zx row stride (fwd 2048 | bwd 2048)
constexpr int NHID = 128;
constexpr int NCHUNK = 16;   // unit-chunks per dir (32 units each)

// packed-weight segment sizes (hi/lo plane buffers laid out [w0f|w0b|w1f|w1b|wl])
constexpr int SW0 = NG4*NIN0P;       // 720896
constexpr int SW1 = NG4*NIN1;        // 2097152
constexpr int SWL = NHID*NIN1;       // 131072
constexpr int SWTOT = 2*SW0 + 2*SW1 + SWL;

typedef __attribute__((ext_vector_type(8))) short short8v;
typedef __attribute__((ext_vector_type(4))) float f32x4;
typedef __attribute__((address_space(3))) unsigned lds_u32;
typedef __attribute__((address_space(1))) const unsigned glb_u32;

__device__ __forceinline__ float sigmoidf_(float x){ return 1.0f/(1.0f+expf(-x)); }
__device__ __forceinline__ short f2bf(float f) {
    union { __hip_bfloat16 h; short s; } u;
    u.h = __float2bfloat16(f);
    return u.s;
}
__device__ __forceinline__ float bf2f(short s) {
    union { unsigned u; float f; } v;
    v.u = ((unsigned)(unsigned short)s) << 16;
    return v.f;
}
__device__ __forceinline__ unsigned packbf3(float v) {
    short hi = f2bf(v);
    short lo = f2bf(v - bf2f(hi));
    return ((unsigned)(unsigned short)hi << 16) | (unsigned short)lo;
}
__device__ __forceinline__ void unpack8(const unsigned* w, short8v& hi, short8v& lo) {
    union U { short8v s; unsigned u[4]; } H, L;
    #pragma unroll
    for (int i = 0; i < 4; i++) {
        H.u[i] = (w[2*i+1] & 0xFFFF0000u) | (w[2*i] >> 16);
        L.u[i] = (w[2*i+1] << 16) | (w[2*i] & 0xFFFFu);
    }
    hi = H.s; lo = L.s;
}
__device__ __forceinline__ unsigned ld_sc1(const unsigned* p) {
    return __hip_atomic_load(p, __ATOMIC_RELAXED, __HIP_MEMORY_SCOPE_AGENT);
}
__device__ __forceinline__ unsigned long long ld64_sc1(const void* p) {
    return __hip_atomic_load((const unsigned long long*)p, __ATOMIC_RELAXED,
                             __HIP_MEMORY_SCOPE_AGENT);
}
__device__ __forceinline__ void st_sc1(unsigned* p, unsigned v) {
    __hip_atomic_store(p, v, __ATOMIC_RELAXED, __HIP_MEMORY_SCOPE_AGENT);
}

// -------- features: word embed + char CNN + concat + relu -> hi/lo bf16 planes ----
__global__ __launch_bounds__(128) void k_features(const int* __restrict__ x_word,
    const float* __restrict__ x_pos, const int* __restrict__ x_char,
    const float* __restrict__ x_enr, const float* __restrict__ wembW,
    const float* __restrict__ cembW, const float* __restrict__ cnnW,
    const float* __restrict__ cnnb,
    unsigned short* __restrict__ xh, unsigned short* __restrict__ xl)
{
    __shared__ float ce[NLC][NCD];
    __shared__ float wT[310*33];
    __shared__ float cv[NCO][14];
    __shared__ float cpool[NCO];
    int n = blockIdx.x;
    int tid = threadIdx.x;
    for (int i = tid; i < NLC*NCD; i += 128) {
        int l = i / NCD, c = i % NCD;
        ce[l][c] = cembW[x_char[n*NLC + l]*NCD + c];
    }
    float acc3[3] = {0.f, 0.f, 0.f};
    #pragma unroll
    for (int half = 0; half < 2; half++) {
        int csta = half*62;
        __syncthreads();
        for (int i = tid; i < 310*32; i += 128) {
            int o = i / 310, ck = i - o*310;
            wT[ck*33 + o] = cnnW[o*(NCD*5) + csta*5 + ck];
        }
        __syncthreads();
        #pragma unroll
        for (int q = 0; q < 3; q++) {
            int p = tid + q*128;
            int o = p & 31, t = p >> 5;
            float acc = acc3[q];
            for (int c = 0; c < 62; c++) {
                #pragma unroll
                for (int k = 0; k < 5; k++)
                    acc += ce[t+k][csta + c] * wT[(c*5+k)*33 + o];
            }
            acc3[q] = acc;
        }
    }
    #pragma unroll
    for (int q = 0; q < 3; q++) {
        int p = tid + q*128;
        cv[p & 31][p >> 5] = acc3[q];
    }
    __syncthreads();
    if (tid < NCO) {
        float m = cv[tid][0];
        #pragma unroll
        for (int t = 1; t < 12; t++) m = fmaxf(m, cv[tid][t]);
        cpool[tid] = m + cnnb[tid];
    }
    __syncthreads();
    int widx = x_word[n];
    for (int j = tid; j < NIN0P; j += 128) {
        float v;
        if (j < NWD)            v = wembW[(size_t)widx*NWD + j];
        else if (j < NWD+NPOS)  v = x_pos[n*NPOS + (j-NWD)];
        else if (j < NWD+NPOS+NCO) v = cpool[j-(NWD+NPOS)];
        else if (j < NIN0)      v = x_enr[n*NENR + (j-(NWD+NPOS+NCO))];
        else                    v = 0.f;
        v = fmaxf(v, 0.f);
        short hi = f2bf(v);
        xh[(size_t)n*NIN0P + j] = (unsigned short)hi;
        xl[(size_t)n*NIN0P + j] = (unsigned short)f2bf(v - bf2f(hi));
    }
}

// -------- pack ALL weights into hi/lo planes in one dispatch ----------------
// dst layout: [w0f(352-pad) | w0b | w1f | w1b | wl]
__global__ void k_pack_all(const float* __restrict__ W0f, const float* __restrict__ W0b,
                           const float* __restrict__ W1f, const float* __restrict__ W1b,
                           const float* __restrict__ WL,
                           unsigned short* __restrict__ Wh, unsigned short* __restrict__ Wl)
{
    int idx = blockIdx.x*256 + threadIdx.x;
    if (idx >= SWTOT) return;
    float v;
    if (idx < 2*SW0) {
        const float* src = (idx < SW0) ? W0f : W0b;
        int loc = (idx < SW0) ? idx : idx - SW0;
        int n = loc / NIN0P, k = loc - n*NIN0P;
        v = (k < NIN0) ? src[(size_t)n*NIN0 + k] : 0.f;
    } else if (idx < 2*SW0 + 2*SW1) {
        int loc = idx - 2*SW0;
        const float* src = (loc < SW1) ? W1f : W1b;
        if (loc >= SW1) loc -= SW1;
        v = src[loc];
    } else {
        v = WL[idx - (2*SW0 + 2*SW1)];
    }
    short hi = f2bf(v);
    Wh[idx] = (unsigned short)hi;
    Wl[idx] = (unsigned short)f2bf(v - bf2f(hi));
}

// -------- split-plane bf16x3 MFMA GEMM (global_load_lds staging, r15) --------
constexpr int HBK = 32;
__global__ __launch_bounds__(256, 2) void k_gemm_hl(
    const unsigned short* __restrict__ Ah, const unsigned short* __restrict__ Al,
    const unsigned short* __restrict__ Bh, const unsigned short* __restrict__ Bl,
    const float* __restrict__ bias, float* __restrict__ C,
    int M, int N, int K)
{
    __shared__ unsigned short sA[2][2][128*HBK];
    __shared__ unsigned short sB[2][2][128*HBK];
    int bx = blockIdx.x, by = blockIdx.y;
    {
        int nMb = gridDim.x, nNb = gridDim.y;
        if (((nMb | nNb) & 3) == 0) {
            int lin = by * nMb + bx;
            int sid = lin >> 4, rem = lin & 15;
            int spr = nNb >> 2;
            int sm = sid / spr, sn = sid - sm*spr;
            bx = sm*4 + (rem >> 2);
            by = sn*4 + (rem & 3);
        }
    }
    int bm = bx*128, bn = by*128;
    int tid = threadIdx.x;
    int l = tid & 63, wv = tid >> 6;
    int wm = wv >> 1, wn = wv & 1;
    int lr = l & 15, lk = l >> 4;

    const unsigned short* gplane = (wv == 0) ? Ah : (wv == 1) ? Al : (wv == 2) ? Bh : Bl;
    int gbase = (wv < 2) ? bm : bn;
    unsigned short* lplane0 = (wv == 0) ? sA[0][0] : (wv == 1) ? sA[0][1]
                           : (wv == 2) ? sB[0][0] : sB[0][1];
    unsigned short* lplane1 = (wv == 0) ? sA[1][0] : (wv == 1) ? sA[1][1]
                           : (wv == 2) ? sB[1][0] : sB[1][1];
    int lrow = l >> 2;
    int gu = (l & 3);

    auto stage = [&](int kt, int buf) {
        unsigned short* lp0 = buf ? lplane1 : lplane0;
        #pragma unroll
        for (int rr = 0; rr < 8; rr++) {
            int row = rr*16 + lrow;
            int guS = gu ^ (row & 3);
            glb_u32* gp = (glb_u32*)(gplane + (size_t)(gbase + row)*K + (size_t)kt*HBK + guS*8);
            lds_u32* lp = (lds_u32*)(lp0 + (rr*16)*HBK);
            __builtin_amdgcn_global_load_lds(gp, lp, 16, 0, 0);
        }
    };

    f32x4 acc[4][4];
    #pragma unroll
    for (int i = 0; i < 4; i++)
        #pragma unroll
        for (int j = 0; j < 4; j++) acc[i][j] = (f32x4){0.f,0.f,0.f,0.f};

    int KT = K / HBK;
    stage(0, 0);
    int cur = 0;
    for (int kt = 0; kt < KT; kt++) {
        __syncthreads();
        if (kt+1 < KT) stage(kt+1, cur^1);
        short8v fAh[4], fAl[4], fBh[4], fBl[4];
        #pragma unroll
        for (int f = 0; f < 4; f++) {
            int ra = wm*64 + f*16 + lr, ua = (lk ^ (ra & 3))*8;
            fAh[f] = *(const short8v*)&sA[cur][0][ra*HBK + ua];
            fAl[f] = *(const short8v*)&sA[cur][1][ra*HBK + ua];
            int rb = wn*64 + f*16 + lr, ub = (lk ^ (rb & 3))*8;
            fBh[f] = *(const short8v*)&sB[cur][0][rb*HBK + ub];
            fBl[f] = *(const short8v*)&sB[cur][1][rb*HBK + ub];
        }
        #pragma unroll
        for (int i = 0; i < 4; i++)
            #pragma unroll
            for (int j = 0; j < 4; j++) {
                acc[i][j] = __builtin_amdgcn_mfma_f32_16x16x32_bf16(fAh[i], fBh[j], acc[i][j], 0, 0, 0);
                acc[i][j] = __builtin_amdgcn_mfma_f32_16x16x32_bf16(fAl[i], fBh[j], acc[i][j], 0, 0, 0);
                acc[i][j] = __builtin_amdgcn_mfma_f32_16x16x32_bf16(fAh[i], fBl[j], acc[i][j], 0, 0, 0);
            }
        cur ^= 1;
    }
    #pragma unroll
    for (int i = 0; i < 4; i++) {
        int m0 = bm + wm*64 + i*16 + lk*4;
        #pragma unroll
        for (int j = 0; j < 4; j++) {
            int n0 = bn + wn*64 + j*16 + lr;
            float bv = bias[n0];
            #pragma unroll
            for (int q = 0; q < 4; q++)
                C[(size_t)(m0+q)*N + n0] = acc[i][j][q] + bv;
        }
    }
}

// -------- head GEMM fused with lin2: em = (h1@lin1W^T + b1) @ lin2W^T + b2 ----
// N = NHID = 128 (grid 64x1): each block holds a full 128x128 hid tile ->
// stage acc into LDS, then compute the 128->18 projection in-kernel.
__global__ __launch_bounds__(256, 1) void k_gemm_head(
    const unsigned short* __restrict__ Ah, const unsigned short* __restrict__ Al,
    const unsigned short* __restrict__ Bh, const unsigned short* __restrict__ Bl,
    const float* __restrict__ bias1, const float* __restrict__ W2,
    const float* __restrict__ b2, float* __restrict__ em, int K)
{
    __shared__ unsigned short sA[2][2][128*HBK];
    __shared__ unsigned short sB[2][2][128*HBK];
    __shared__ float hidS[128*132];    // 67.6 KB
    __shared__ float w2S[NT*132];      // 9.3 KB
    __shared__ float b2S[NT];
    int bm = blockIdx.x*128;
    int tid = threadIdx.x;
    int l = tid & 63, wv = tid >> 6;
    int wm = wv >> 1, wn = wv & 1;
    int lr = l & 15, lk = l >> 4;

    for (int i = tid; i < NT*NHID; i += 256) {
        int j = i >> 7, k = i & 127;
        w2S[j*132 + k] = W2[i];
    }
    if (tid < NT) b2S[tid] = b2[tid];

    const unsigned short* gplane = (wv == 0) ? Ah : (wv == 1) ? Al : (wv == 2) ? Bh : Bl;
    int gbase = (wv < 2) ? bm : 0;
    unsigned short* lplane0 = (wv == 0) ? sA[0][0] : (wv == 1) ? sA[0][1]
                           : (wv == 2) ? sB[0][0] : sB[0][1];
    unsigned short* lplane1 = (wv == 0) ? sA[1][0] : (wv == 1) ? sA[1][1]
                           : (wv == 2) ? sB[1][0] : sB[1][1];
    int lrow = l >> 2;
    int gu = (l & 3);

    auto stage = [&](int kt, int buf) {
        unsigned short* lp0 = buf ? lplane1 : lplane0;
        #pragma unroll
        for (int rr = 0; rr < 8; rr++) {
            int row = rr*16 + lrow;
            int guS = gu ^ (row & 3);
            glb_u32* gp = (glb_u32*)(gplane + (size_t)(gbase + row)*K + (size_t)kt*HBK + guS*8);
            lds_u32* lp = (lds_u32*)(lp0 + (rr*16)*HBK);
            __builtin_amdgcn_global_load_lds(gp, lp, 16, 0, 0);
        }
    };

    f32x4 acc[4][4];
    #pragma unroll
    for (int i = 0; i < 4; i++)
        #pragma unroll
        for (int j = 0; j < 4; j++) acc[i][j] = (f32x4){0.f,0.f,0.f,0.f};

    int KT = K / HBK;
    stage(0, 0);
    int cur = 0;
    for (int kt = 0; kt < KT; kt++) {
        __syncthreads();
        if (kt+1 < KT) stage(kt+1, cur^1);
        short8v fAh[4], fAl[4], fBh[4], fBl[4];
        #pragma unroll
        for (int f = 0; f < 4; f++) {
            int ra = wm*64 + f*16 + lr, ua = (lk ^ (ra & 3))*8;
            fAh[f] = *(const short8v*)&sA[cur][0][ra*HBK + ua];
            fAl[f] = *(const short8v*)&sA[cur][1][ra*HBK + ua];
            int rb = wn*64 + f*16 + lr, ub = (lk ^ (rb & 3))*8;
            fBh[f] = *(const short8v*)&sB[cur][0][rb*HBK + ub];
            fBl[f] = *(const short8v*)&sB[cur][1][rb*HBK + ub];
        }
        #pragma unroll
        for (int i = 0; i < 4; i++)
            #pragma unroll
            for (int j = 0; j < 4; j++) {
                acc[i][j] = __builtin_amdgcn_mfma_f32_16x16x32_bf16(fAh[i], fBh[j], acc[i][j], 0, 0, 0);
                acc[i][j] = __builtin_amdgcn_mfma_f32_16x16x32_bf16(fAl[i], fBh[j], acc[i][j], 0, 0, 0);
                acc[i][j] = __builtin_amdgcn_mfma_f32_16x16x32_bf16(fAh[i], fBl[j], acc[i][j], 0, 0, 0);
            }
        cur ^= 1;
    }
    // stage hid tile (+bias1) to LDS
    #pragma unroll
    for (int i = 0; i < 4; i++) {
        int mloc = wm*64 + i*16 + lk*4;
        #pragma unroll
        for (int j = 0; j < 4; j++) {
            int nloc = wn*64 + j*16 + lr;
            float bv = bias1[nloc];
            #pragma unroll
            for (int q = 0; q < 4; q++)
                hidS[(mloc+q)*132 + nloc] = acc[i][j][q] + bv;
        }
    }
    __syncthreads();
    // em = hid @ W2^T + b2  (2304 outputs / 256 threads)
    for (int oi = tid; oi < 128*NT; oi += 256) {
        int m = oi / NT, j = oi - m*NT;
        const float* hr = &hidS[m*132];
        const float* wr = &w2S[j*132];
        float s = b2S[j];
        #pragma unroll 8
        for (int k = 0; k < NHID; k += 4) {
            float4 h4 = *(const float4*)(hr+k);
            float4 w4 = *(const float4*)(wr+k);
            s += h4.x*w4.x + h4.y*w4.y + h4.z*w4.z + h4.w*w4.w;
        }
        em[(size_t)(bm+m)*NT + j] = s;
    }
}

// ---------------- persistent LSTM layer: r12 structure, barrier C removed ------
// Per-wave release: s_waitcnt vmcnt(0) + per-wave flag (128 dense flags/dir).
// Safety: barrier B protects hstage; barrier A(t+1) protects zsh (audited r16).
__global__ __launch_bounds__(512, 2) void k_lstm_layer(
    const float* __restrict__ zxcat,
    const float* __restrict__ Whh_f, const float* __restrict__ Whh_b,
    unsigned short* __restrict__ h_hi, unsigned short* __restrict__ h_lo,
    unsigned* __restrict__ hbf, unsigned* __restrict__ flags)
{
    int chunk = blockIdx.x;
    int dir   = blockIdx.y;
    int tid = threadIdx.x;
    int wv = tid >> 6, l = tid & 63;
    int g  = wv & 3;
    int ks = wv >> 2;
    int lr = l & 15, lk = l >> 4;
    const float* zx  = zxcat + dir*NG4;
    const float* Whh = dir ? Whh_b : Whh_f;
    unsigned* hb = hbf + (size_t)dir * (2*NB*NH);
    unsigned* flag = flags + (size_t)dir * (NCHUNK*8);   // dense [chunk][wave]

    short8v bwh[2][8], bwl[2][8];
    #pragma unroll
    for (int uh = 0; uh < 2; uh++) {
        const float* wrow = Whh + ((size_t)(g*NH + chunk*32 + uh*16 + lr))*NH + ks*256 + lk*8;
        #pragma unroll
        for (int kt = 0; kt < 8; kt++) {
            float u[8];
            *(float4*)&u[0] = *(const float4*)(wrow + kt*32);
            *(float4*)&u[4] = *(const float4*)(wrow + kt*32 + 4);
            short8v sh, sl;
            #pragma unroll
            for (int j = 0; j < 8; j++) {
                short hi = f2bf(u[j]);
                sh[j] = hi;
                sl[j] = f2bf(u[j] - bf2f(hi));
            }
            bwh[uh][kt] = sh; bwl[uh][kt] = sl;
        }
    }

    __shared__ unsigned hstage[32*516];
    __shared__ float zsh[2][4][32][33];
    float c0 = 0.f, c1 = 0.f;

    for (int t = 0; t < NS; t++) {
        int t_eff = dir ? (NS-1-t) : t;

        float pz[2][4];
        #pragma unroll
        for (int cc = 0; cc < 2; cc++) {
            int cell = tid + cc*512, b = cell >> 5, u = cell & 31;
            const float* zr = zx + ((size_t)(b*NS + t_eff))*NGS + chunk*32 + u;
            #pragma unroll
            for (int g2 = 0; g2 < 4; g2++) pz[cc][g2] = zr[g2*NH];
        }

        if (t > 0) {
            {   // poll all 128 per-wave flags (2 per lane via u64)
                const unsigned long long* fp = (const unsigned long long*)flag + l;
                unsigned tv = (unsigned)t;
                unsigned long long v;
                do { v = ld64_sc1(fp); }
                while (!__all(((unsigned)v >= tv) && ((unsigned)(v>>32) >= tv)));
                asm volatile("" ::: "memory");
            }
            const unsigned* hp = hb + ((t-1)&1)*(NB*NH);
            unsigned sv[32];
            #pragma unroll
            for (int i = 0; i < 32; i++) sv[i] = ld_sc1(hp + i*512 + tid);
            #pragma unroll
            for (int i = 0; i < 32; i++) hstage[i*516 + tid] = sv[i];
        }
        __syncthreads();   // barrier A: stage visible (also protects zsh of t-1)

        f32x4 acc[2][2][3];
        #pragma unroll
        for (int bh = 0; bh < 2; bh++)
            #pragma unroll
            for (int uh = 0; uh < 2; uh++)
                #pragma unroll
                for (int q = 0; q < 3; q++) acc[bh][uh][q] = (f32x4){0.f,0.f,0.f,0.f};
        if (t > 0) {
            #pragma unroll
            for (int kt = 0; kt < 8; kt++) {
                short8v ah[2], al[2];
                #pragma unroll
                for (int bh = 0; bh < 2; bh++) {
                    unsigned w8[8];
                    const unsigned* sp = hstage + (bh*16+lr)*516 + ks*256 + kt*32 + lk*8;
                    *(uint4*)&w8[0] = *(const uint4*)sp;
                    *(uint4*)&w8[4] = *(const uint4*)(sp+4);
                    unpack8(w8, ah[bh], al[bh]);
                }
                #pragma unroll
                for (int bh = 0; bh < 2; bh++)
                    #pragma unroll
                    for (int uh = 0; uh < 2; uh++) {
                        acc[bh][uh][0] = __builtin_amdgcn_mfma_f32_16x16x32_bf16(ah[bh], bwh[uh][kt], acc[bh][uh][0], 0, 0, 0);
                        acc[bh][uh][1] = __builtin_amdgcn_mfma_f32_16x16x32_bf16(al[bh], bwh[uh][kt], acc[bh][uh][1], 0, 0, 0);
                        acc[bh][uh][2] = __builtin_amdgcn_mfma_f32_16x16x32_bf16(ah[bh], bwl[uh][kt], acc[bh][uh][2], 0, 0, 0);
                    }
            }
        }
        #pragma unroll
        for (int bh = 0; bh < 2; bh++)
            #pragma unroll
            for (int uh = 0; uh < 2; uh++)
                #pragma unroll
                for (int j = 0; j < 4; j++)
                    zsh[ks][g][bh*16 + lk*4 + j][uh*16 + lr] =
                        acc[bh][uh][0][j] + acc[bh][uh][1][j] + acc[bh][uh][2][j];
        __syncthreads();   // barrier B: zsh ready (also protects hstage)

        unsigned hq0 = 0, hq1 = 0;
        #pragma unroll
        for (int cc = 0; cc < 2; cc++) {
            int cell = tid + cc*512, b = cell >> 5, u = cell & 31;
            float zi = pz[cc][0] + zsh[0][0][b][u] + zsh[1][0][b][u];
            float zf = pz[cc][1] + zsh[0][1][b][u] + zsh[1][1][b][u];
            float zg = pz[cc][2] + zsh[0][2][b][u] + zsh[1][2][b][u];
            float zo = pz[cc][3] + zsh[0][3][b][u] + zsh[1][3][b][u];
            float cold = cc ? c1 : c0;
            float cn = sigmoidf_(zf)*cold + sigmoidf_(zi)*tanhf(zg);
            float hn = sigmoidf_(zo)*tanhf(cn);
            unsigned pk = packbf3(hn);
            if (cc) { c1 = cn; hq1 = pk; } else { c0 = cn; hq0 = pk; }
            st_sc1(&hb[(size_t)(t&1)*(NB*NH) + b*NH + chunk*32 + u], pk);
        }
        // per-wave release (barrier C deleted): own stores acked, then own flag
        asm volatile("s_waitcnt vmcnt(0)" ::: "memory");
        if (l == 0) st_sc1(&flag[chunk*8 + wv], (unsigned)(t+1));
        #pragma unroll
        for (int cc = 0; cc < 2; cc++) {
            int cell = tid + cc*512, b = cell >> 5, u = cell & 31;
            unsigned pk = cc ? hq1 : hq0;
            size_t o = ((size_t)(b*NS + t_eff))*NIN1 + dir*NH + chunk*32 + u;
            h_hi[o] = (unsigned short)(pk >> 16);
            h_lo[o] = (unsigned short)(pk & 0xFFFFu);
        }
    }
}

// ---------------- fused CRF: viterbi decode + NLL forward in one pass ---------
__global__ __launch_bounds__(64) void k_crf(const float* __restrict__ em,
    const int* __restrict__ tags, const float* __restrict__ start,
    const float* __restrict__ endv, const float* __restrict__ trans,
    float* __restrict__ dec, float* __restrict__ partial)
{
    __shared__ float tr[NT][NT];
    __shared__ float vsc[NT], nsc[NT];
    __shared__ unsigned char hist[NS][NT];
    __shared__ float numsh;
    int b = blockIdx.x, tid = threadIdx.x;
    for (int i = tid; i < NT*NT; i += 64) tr[i/NT][i%NT] = trans[i];
    if (tid < NT) {
        float e0 = em[((size_t)b*NS)*NT + tid];
        vsc[tid] = start[tid] + e0;
        nsc[tid] = start[tid] + e0;
    }
    __syncthreads();
    const int* tg = tags + b*NS;
    float num = 0.f;
    for (int t = 1; t < NS; t++) {
        float nv_v = 0.f, nv_n = 0.f;
        if (tid < NT) {
            float emv = em[((size_t)b*NS + t)*NT + tid];
            float best = -1e30f; int bi = 0;
            float m = -1e30f;
            for (int i = 0; i < NT; i++) {
                float v = vsc[i] + tr[i][tid];
                if (v > best) { best = v; bi = i; }
                m = fmaxf(m, nsc[i] + tr[i][tid]);
            }
            hist[t][tid] = (unsigned char)bi;
            nv_v = best + emv;
            float s = 0.f;
            for (int i = 0; i < NT; i++) s += expf(nsc[i] + tr[i][tid] - m);
            nv_n = m + logf(s) + emv;
        } else if (tid == 32) {
            num += tr[tg[t-1]][tg[t]] + em[((size_t)b*NS + t)*NT + tg[t]];
        }
        __syncthreads();
        if (tid < NT) { vsc[tid] = nv_v; nsc[tid] = nv_n; }
        __syncthreads();
    }
    if (tid == 32) numsh = num;
    __syncthreads();
    if (tid == 0) {
        float bv = vsc[0] + endv[0]; int tag = 0;
        for (int j = 1; j < NT; j++) { float v = vsc[j] + endv[j]; if (v > bv) { bv = v; tag = j; } }
        dec[b*NS + NS-1] = (float)tag;
        for (int t = NS-1; t >= 1; t--) { tag = hist[t][tag]; dec[b*NS + t-1] = (float)tag; }
        float m = -1e30f;
        for (int j = 0; j < NT; j++) m = fmaxf(m, nsc[j] + endv[j]);
        float s = 0.f;
        for (int j = 0; j < NT; j++) s += expf(nsc[j] + endv[j] - m);
        float logZ = m + logf(s);
        float numer = start[tg[0]] + em[((size_t)b*NS)*NT + tg[0]] + numsh + endv[tg[NS-1]];
        partial[b] = -(numer - logZ);
    }
}

__global__ void k_loss_final(const float* __restrict__ partial, float* __restrict__ loss)
{
    if (threadIdx.x == 0 && blockIdx.x == 0) {
        float s = 0.f;
        for (int b = 0; b < NB; b++) s += partial[b];
        *loss = s / (float)(NB*NS);
    }
}

extern "C" void kernel_launch(void* const* d_in, const int* in_sizes, int n_in,
                              void* d_out, int out_size, void* d_ws, size_t ws_size,
                              hipStream_t stream)
{
    const int*   x_word = (const int*)d_in[0];
    const float* x_pos  = (const float*)d_in[1];
    const int*   x_char = (const int*)d_in[2];
    const float* x_enr  = (const float*)d_in[3];
    const int*   y_word = (const int*)d_in[5];
    const float* wembW  = (const float*)d_in[6];
    const float* cembW  = (const float*)d_in[7];
    const float* cnnW   = (const float*)d_in[8];
    const float* cnnb   = (const float*)d_in[9];
    const float* lin1W  = (const float*)d_in[10];
    const float* lin1b  = (const float*)d_in[11];
    const float* lin2W  = (const float*)d_in[12];
    const float* lin2b  = (const float*)d_in[13];
    const float* crf_s  = (const float*)d_in[14];
    const float* crf_e  = (const float*)d_in[15];
    const float* crf_tr = (const float*)d_in[16];
    const float* l0f_Wih = (const float*)d_in[17];
    const float* l0f_Whh = (const float*)d_in[18];
    const float* l0f_b   = (const float*)d_in[19];
    const float* l0b_Wih = (const float*)d_in[20];
    const float* l0b_Whh = (const float*)d_in[21];
    const float* l0b_b   = (const float*)d_in[22];
    const float* l1f_Wih = (const float*)d_in[23];
    const float* l1f_Whh = (const float*)d_in[24];
    const float* l1f_b   = (const float*)d_in[25];
    const float* l1b_Wih = (const float*)d_in[26];
    const float* l1b_Whh = (const float*)d_in[27];
    const float* l1b_b   = (const float*)d_in[28];

    char* wsb = (char*)d_ws;
    size_t off = 0;
    auto alloc = [&](size_t bytes) { char* p = wsb + off; off += (bytes + 255) & ~(size_t)255; return p; };
    unsigned short* xh  = (unsigned short*)alloc((size_t)NBS*NIN0P*2);
    unsigned short* xl  = (unsigned short*)alloc((size_t)NBS*NIN0P*2);
    unsigned short* whA = (unsigned short*)alloc((size_t)SWTOT*2);
    unsigned short* wlA = (unsigned short*)alloc((size_t)SWTOT*2);
    float*    zxcat = (float*)alloc((size_t)NBS*NGS*4);
    unsigned short* h0h = (unsigned short*)alloc((size_t)NBS*NIN1*2);
    unsigned short* h0l = (unsigned short*)alloc((size_t)NBS*NIN1*2);
    unsigned short* h1h = (unsigned short*)alloc((size_t)NBS*NIN1*2);
    unsigned short* h1l = (unsigned short*)alloc((size_t)NBS*NIN1*2);
    float*    partial = (float*)alloc(256);
    float*    bias0 = (float*)alloc((size_t)NGS*4);
    float*    bias1 = (float*)alloc((size_t)NGS*4);
    unsigned* hbf   = (unsigned*)alloc((size_t)2*2*NB*NH*4);
    unsigned* flags = (unsigned*)alloc((size_t)2*NCHUNK*8*4);

    unsigned short* w0h = whA;
    unsigned short* w1h = whA + 2*(size_t)SW0;
    unsigned short* wlh = whA + 2*(size_t)SW0 + 2*(size_t)SW1;
    unsigned short* w0l = wlA;
    unsigned short* w1l = wlA + 2*(size_t)SW0;
    unsigned short* wll = wlA + 2*(size_t)SW0 + 2*(size_t)SW1;

    float* em_out   = (float*)d_out;
    float* dec_out  = em_out + (size_t)NBS*NT;
    float* loss_out = dec_out + NBS;

    // 1. pack ALL weights (one dispatch)
    k_pack_all<<<(SWTOT+255)/256, 256, 0, stream>>>(l0f_Wih, l0b_Wih, l1f_Wih, l1b_Wih,
                                                    lin1W, whA, wlA);
    // cat biases
    hipMemcpyAsync(bias0,       l0f_b, NG4*4, hipMemcpyDeviceToDevice, stream);
    hipMemcpyAsync(bias0 + NG4, l0b_b, NG4*4, hipMemcpyDeviceToDevice, stream);
    hipMemcpyAsync(bias1,       l1f_b, NG4*4, hipMemcpyDeviceToDevice, stream);
    hipMemcpyAsync(bias1 + NG4, l1b_b, NG4*4, hipMemcpyDeviceToDevice, stream);
    // 2. features (hi/lo planes)
    k_features<<<NBS, 128, 0, stream>>>(x_word, x_pos, x_char, x_enr, wembW, cembW, cnnW, cnnb, xh, xl);
    // 3. layer-0 fused input projection (both dirs, N=4096)
    k_gemm_hl<<<dim3(NBS/128, NGS/128), 256, 0, stream>>>(xh, xl, w0h, w0l, bias0, zxcat, NBS, NGS, NIN0P);
    // 4. layer-0 recurrence
    hipMemsetAsync(flags, 0, (size_t)2*NCHUNK*8*4, stream);
    k_lstm_layer<<<dim3(NCHUNK, 2), 512, 0, stream>>>(zxcat, l0f_Whh, l0b_Whh, h0h, h0l, hbf, flags);
    // 5. layer-1 fused input projection
    k_gemm_hl<<<dim3(NBS/128, NGS/128), 256, 0, stream>>>(h0h, h0l, w1h, w1l, bias1, zxcat, NBS, NGS, NIN1);
    // 6. layer-1 recurrence
    hipMemsetAsync(flags, 0, (size_t)2*NCHUNK*8*4, stream);
    k_lstm_layer<<<dim3(NCHUNK, 2), 512, 0, stream>>>(zxcat, l1f_Whh, l1b_Whh, h1h, h1l, hbf, flags);
    // 7. head GEMM fused with lin2 -> em
    k_gemm_head<<<NBS/128, 256, 0, stream>>>(h1h, h1l, wlh, wll, lin1b, lin2W, lin2b, em_out, NIN1);
    // 8. CRF (fused viterbi + nll)
    k_crf<<<NB, 64, 0, stream>>>(em_out, y_word, crf_s, crf_e, crf_tr, dec_out, partial);
    k_loss_final<<<1, 64, 0, stream>>>(partial, loss_out);
}

// Round 17
// 3604.623 us; speedup vs baseline: 1.3759x; 1.3759x over previous
//
#include <hip/hip_runtime.h>
#include <hip/hip_bf16.h>
#include <math.h>

// ---- problem dims ----
constexpr int NB   = 32;
constexpr int NS   = 256;
constexpr int NLC  = 16;
constexpr int NWD  = 256;
constexpr int NCD  = 124;
constexpr int NCO  = 32;
constexpr int NPOS = 36;
constexpr int NENR = 7;
constexpr int NH   = 512;
constexpr int NT   = 18;
constexpr int NIN0 = 331;
constexpr int NIN0P= 352;    // padded to x32
constexpr int NIN1 = 1024;
constexpr int NBS  = NB*NS;  // 8192
constexpr int NG4  = 4*NH;   // 2048
constexpr int NGS  = 4096;   // fused zx row stride (fwd 2048 | bwd 2048)
constexpr int NHID = 128;
constexpr int NCHUNK = 16;   // unit-chunks per dir (32 units each)

// packed-weight segment sizes (hi/lo plane buffers laid out [w0f|w0b|w1f|w1b|wl])
constexpr int SW0 = NG4*NIN0P;
constexpr int SW1 = NG4*NIN1;
constexpr int SWL = NHID*NIN1;
constexpr int SWTOT = 2*SW0 + 2*SW1 + SWL;

typedef __attribute__((ext_vector_type(8))) short short8v;
typedef __attribute__((ext_vector_type(4))) float f32x4;
typedef __attribute__((address_space(3))) unsigned lds_u32;
typedef __attribute__((address_space(1))) const unsigned glb_u32;

__device__ __forceinline__ float sigmoidf_(float x){ return 1.0f/(1.0f+expf(-x)); }
__device__ __forceinline__ short f2bf(float f) {
    union { __hip_bfloat16 h; short s; } u;
    u.h = __float2bfloat16(f);
    return u.s;
}
__device__ __forceinline__ float bf2f(short s) {
    union { unsigned u; float f; } v;
    v.u = ((unsigned)(unsigned short)s) << 16;
    return v.f;
}
__device__ __forceinline__ unsigned packbf3(float v) {
    short hi = f2bf(v);
    short lo = f2bf(v - bf2f(hi));
    return ((unsigned)(unsigned short)hi << 16) | (unsigned short)lo;
}
__device__ __forceinline__ void unpack8(const unsigned* w, short8v& hi, short8v& lo) {
    union U { short8v s; unsigned u[4]; } H, L;
    #pragma unroll
    for (int i = 0; i < 4; i++) {
        H.u[i] = (w[2*i+1] & 0xFFFF0000u) | (w[2*i] >> 16);
        L.u[i] = (w[2*i+1] << 16) | (w[2*i] & 0xFFFFu);
    }
    hi = H.s; lo = L.s;
}
__device__ __forceinline__ unsigned ld_sc1(const unsigned* p) {
    return __hip_atomic_load(p, __ATOMIC_RELAXED, __HIP_MEMORY_SCOPE_AGENT);
}
__device__ __forceinline__ void st_sc1(unsigned* p, unsigned v) {
    __hip_atomic_store(p, v, __ATOMIC_RELAXED, __HIP_MEMORY_SCOPE_AGENT);
}

// -------- features: word embed + char CNN + concat + relu -> hi/lo bf16 planes ----
__global__ __launch_bounds__(128) void k_features(const int* __restrict__ x_word,
    const float* __restrict__ x_pos, const int* __restrict__ x_char,
    const float* __restrict__ x_enr, const float* __restrict__ wembW,
    const float* __restrict__ cembW, const float* __restrict__ cnnW,
    const float* __restrict__ cnnb,
    unsigned short* __restrict__ xh, unsigned short* __restrict__ xl)
{
    __shared__ float ce[NLC][NCD];
    __shared__ float wT[310*33];
    __shared__ float cv[NCO][14];
    __shared__ float cpool[NCO];
    int n = blockIdx.x;
    int tid = threadIdx.x;
    for (int i = tid; i < NLC*NCD; i += 128) {
        int l = i / NCD, c = i % NCD;
        ce[l][c] = cembW[x_char[n*NLC + l]*NCD + c];
    }
    float acc3[3] = {0.f, 0.f, 0.f};
    #pragma unroll
    for (int half = 0; half < 2; half++) {
        int csta = half*62;
        __syncthreads();
        for (int i = tid; i < 310*32; i += 128) {
            int o = i / 310, ck = i - o*310;
            wT[ck*33 + o] = cnnW[o*(NCD*5) + csta*5 + ck];
        }
        __syncthreads();
        #pragma unroll
        for (int q = 0; q < 3; q++) {
            int p = tid + q*128;
            int o = p & 31, t = p >> 5;
            float acc = acc3[q];
            for (int c = 0; c < 62; c++) {
                #pragma unroll
                for (int k = 0; k < 5; k++)
                    acc += ce[t+k][csta + c] * wT[(c*5+k)*33 + o];
            }
            acc3[q] = acc;
        }
    }
    #pragma unroll
    for (int q = 0; q < 3; q++) {
        int p = tid + q*128;
        cv[p & 31][p >> 5] = acc3[q];
    }
    __syncthreads();
    if (tid < NCO) {
        float m = cv[tid][0];
        #pragma unroll
        for (int t = 1; t < 12; t++) m = fmaxf(m, cv[tid][t]);
        cpool[tid] = m + cnnb[tid];
    }
    __syncthreads();
    int widx = x_word[n];
    for (int j = tid; j < NIN0P; j += 128) {
        float v;
        if (j < NWD)            v = wembW[(size_t)widx*NWD + j];
        else if (j < NWD+NPOS)  v = x_pos[n*NPOS + (j-NWD)];
        else if (j < NWD+NPOS+NCO) v = cpool[j-(NWD+NPOS)];
        else if (j < NIN0)      v = x_enr[n*NENR + (j-(NWD+NPOS+NCO))];
        else                    v = 0.f;
        v = fmaxf(v, 0.f);
        short hi = f2bf(v);
        xh[(size_t)n*NIN0P + j] = (unsigned short)hi;
        xl[(size_t)n*NIN0P + j] = (unsigned short)f2bf(v - bf2f(hi));
    }
}

// -------- pack ALL weights into hi/lo planes in one dispatch ----------------
__global__ void k_pack_all(const float* __restrict__ W0f, const float* __restrict__ W0b,
                           const float* __restrict__ W1f, const float* __restrict__ W1b,
                           const float* __restrict__ WL,
                           unsigned short* __restrict__ Wh, unsigned short* __restrict__ Wl)
{
    int idx = blockIdx.x*256 + threadIdx.x;
    if (idx >= SWTOT) return;
    float v;
    if (idx < 2*SW0) {
        const float* src = (idx < SW0) ? W0f : W0b;
        int loc = (idx < SW0) ? idx : idx - SW0;
        int n = loc / NIN0P, k = loc - n*NIN0P;
        v = (k < NIN0) ? src[(size_t)n*NIN0 + k] : 0.f;
    } else if (idx < 2*SW0 + 2*SW1) {
        int loc = idx - 2*SW0;
        const float* src = (loc < SW1) ? W1f : W1b;
        if (loc >= SW1) loc -= SW1;
        v = src[loc];
    } else {
        v = WL[idx - (2*SW0 + 2*SW1)];
    }
    short hi = f2bf(v);
    Wh[idx] = (unsigned short)hi;
    Wl[idx] = (unsigned short)f2bf(v - bf2f(hi));
}

// -------- split-plane bf16x3 MFMA GEMM (global_load_lds staging, r15) --------
constexpr int HBK = 32;
__global__ __launch_bounds__(256, 2) void k_gemm_hl(
    const unsigned short* __restrict__ Ah, const unsigned short* __restrict__ Al,
    const unsigned short* __restrict__ Bh, const unsigned short* __restrict__ Bl,
    const float* __restrict__ bias, float* __restrict__ C,
    int M, int N, int K)
{
    __shared__ unsigned short sA[2][2][128*HBK];
    __shared__ unsigned short sB[2][2][128*HBK];
    int bx = blockIdx.x, by = blockIdx.y;
    {
        int nMb = gridDim.x, nNb = gridDim.y;
        if (((nMb | nNb) & 3) == 0) {
            int lin = by * nMb + bx;
            int sid = lin >> 4, rem = lin & 15;
            int spr = nNb >> 2;
            int sm = sid / spr, sn = sid - sm*spr;
            bx = sm*4 + (rem >> 2);
            by = sn*4 + (rem & 3);
        }
    }
    int bm = bx*128, bn = by*128;
    int tid = threadIdx.x;
    int l = tid & 63, wv = tid >> 6;
    int wm = wv >> 1, wn = wv & 1;
    int lr = l & 15, lk = l >> 4;

    const unsigned short* gplane = (wv == 0) ? Ah : (wv == 1) ? Al : (wv == 2) ? Bh : Bl;
    int gbase = (wv < 2) ? bm : bn;
    unsigned short* lplane0 = (wv == 0) ? sA[0][0] : (wv == 1) ? sA[0][1]
                           : (wv == 2) ? sB[0][0] : sB[0][1];
    unsigned short* lplane1 = (wv == 0) ? sA[1][0] : (wv == 1) ? sA[1][1]
                           : (wv == 2) ? sB[1][0] : sB[1][1];
    int lrow = l >> 2;
    int gu = (l & 3);

    auto stage = [&](int kt, int buf) {
        unsigned short* lp0 = buf ? lplane1 : lplane0;
        #pragma unroll
        for (int rr = 0; rr < 8; rr++) {
            int row = rr*16 + lrow;
            int guS = gu ^ (row & 3);
            glb_u32* gp = (glb_u32*)(gplane + (size_t)(gbase + row)*K + (size_t)kt*HBK + guS*8);
            lds_u32* lp = (lds_u32*)(lp0 + (rr*16)*HBK);
            __builtin_amdgcn_global_load_lds(gp, lp, 16, 0, 0);
        }
    };

    f32x4 acc[4][4];
    #pragma unroll
    for (int i = 0; i < 4; i++)
        #pragma unroll
        for (int j = 0; j < 4; j++) acc[i][j] = (f32x4){0.f,0.f,0.f,0.f};

    int KT = K / HBK;
    stage(0, 0);
    int cur = 0;
    for (int kt = 0; kt < KT; kt++) {
        __syncthreads();
        if (kt+1 < KT) stage(kt+1, cur^1);
        short8v fAh[4], fAl[4], fBh[4], fBl[4];
        #pragma unroll
        for (int f = 0; f < 4; f++) {
            int ra = wm*64 + f*16 + lr, ua = (lk ^ (ra & 3))*8;
            fAh[f] = *(const short8v*)&sA[cur][0][ra*HBK + ua];
            fAl[f] = *(const short8v*)&sA[cur][1][ra*HBK + ua];
            int rb = wn*64 + f*16 + lr, ub = (lk ^ (rb & 3))*8;
            fBh[f] = *(const short8v*)&sB[cur][0][rb*HBK + ub];
            fBl[f] = *(const short8v*)&sB[cur][1][rb*HBK + ub];
        }
        #pragma unroll
        for (int i = 0; i < 4; i++)
            #pragma unroll
            for (int j = 0; j < 4; j++) {
                acc[i][j] = __builtin_amdgcn_mfma_f32_16x16x32_bf16(fAh[i], fBh[j], acc[i][j], 0, 0, 0);
                acc[i][j] = __builtin_amdgcn_mfma_f32_16x16x32_bf16(fAl[i], fBh[j], acc[i][j], 0, 0, 0);
                acc[i][j] = __builtin_amdgcn_mfma_f32_16x16x32_bf16(fAh[i], fBl[j], acc[i][j], 0, 0, 0);
            }
        cur ^= 1;
    }
    #pragma unroll
    for (int i = 0; i < 4; i++) {
        int m0 = bm + wm*64 + i*16 + lk*4;
        #pragma unroll
        for (int j = 0; j < 4; j++) {
            int n0 = bn + wn*64 + j*16 + lr;
            float bv = bias[n0];
            #pragma unroll
            for (int q = 0; q < 4; q++)
                C[(size_t)(m0+q)*N + n0] = acc[i][j][q] + bv;
        }
    }
}

// -------- head GEMM fused with lin2: em = (h1@lin1W^T + b1) @ lin2W^T + b2 ----
__global__ __launch_bounds__(256, 1) void k_gemm_head(
    const unsigned short* __restrict__ Ah, const unsigned short* __restrict__ Al,
    const unsigned short* __restrict__ Bh, const unsigned short* __restrict__ Bl,
    const float* __restrict__ bias1, const float* __restrict__ W2,
    const float* __restrict__ b2, float* __restrict__ em, int K)
{
    __shared__ unsigned short sA[2][2][128*HBK];
    __shared__ unsigned short sB[2][2][128*HBK];
    __shared__ float hidS[128*132];
    __shared__ float w2S[NT*132];
    __shared__ float b2S[NT];
    int bm = blockIdx.x*128;
    int tid = threadIdx.x;
    int l = tid & 63, wv = tid >> 6;
    int wm = wv >> 1, wn = wv & 1;
    int lr = l & 15, lk = l >> 4;

    for (int i = tid; i < NT*NHID; i += 256) {
        int j = i >> 7, k = i & 127;
        w2S[j*132 + k] = W2[i];
    }
    if (tid < NT) b2S[tid] = b2[tid];

    const unsigned short* gplane = (wv == 0) ? Ah : (wv == 1) ? Al : (wv == 2) ? Bh : Bl;
    int gbase = (wv < 2) ? bm : 0;
    unsigned short* lplane0 = (wv == 0) ? sA[0][0] : (wv == 1) ? sA[0][1]
                           : (wv == 2) ? sB[0][0] : sB[0][1];
    unsigned short* lplane1 = (wv == 0) ? sA[1][0] : (wv == 1) ? sA[1][1]
                           : (wv == 2) ? sB[1][0] : sB[1][1];
    int lrow = l >> 2;
    int gu = (l & 3);

    auto stage = [&](int kt, int buf) {
        unsigned short* lp0 = buf ? lplane1 : lplane0;
        #pragma unroll
        for (int rr = 0; rr < 8; rr++) {
            int row = rr*16 + lrow;
            int guS = gu ^ (row & 3);
            glb_u32* gp = (glb_u32*)(gplane + (size_t)(gbase + row)*K + (size_t)kt*HBK + guS*8);
            lds_u32* lp = (lds_u32*)(lp0 + (rr*16)*HBK);
            __builtin_amdgcn_global_load_lds(gp, lp, 16, 0, 0);
        }
    };

    f32x4 acc[4][4];
    #pragma unroll
    for (int i = 0; i < 4; i++)
        #pragma unroll
        for (int j = 0; j < 4; j++) acc[i][j] = (f32x4){0.f,0.f,0.f,0.f};

    int KT = K / HBK;
    stage(0, 0);
    int cur = 0;
    for (int kt = 0; kt < KT; kt++) {
        __syncthreads();
        if (kt+1 < KT) stage(kt+1, cur^1);
        short8v fAh[4], fAl[4], fBh[4], fBl[4];
        #pragma unroll
        for (int f = 0; f < 4; f++) {
            int ra = wm*64 + f*16 + lr, ua = (lk ^ (ra & 3))*8;
            fAh[f] = *(const short8v*)&sA[cur][0][ra*HBK + ua];
            fAl[f] = *(const short8v*)&sA[cur][1][ra*HBK + ua];
            int rb = wn*64 + f*16 + lr, ub = (lk ^ (rb & 3))*8;
            fBh[f] = *(const short8v*)&sB[cur][0][rb*HBK + ub];
            fBl[f] = *(const short8v*)&sB[cur][1][rb*HBK + ub];
        }
        #pragma unroll
        for (int i = 0; i < 4; i++)
            #pragma unroll
            for (int j = 0; j < 4; j++) {
                acc[i][j] = __builtin_amdgcn_mfma_f32_16x16x32_bf16(fAh[i], fBh[j], acc[i][j], 0, 0, 0);
                acc[i][j] = __builtin_amdgcn_mfma_f32_16x16x32_bf16(fAl[i], fBh[j], acc[i][j], 0, 0, 0);
                acc[i][j] = __builtin_amdgcn_mfma_f32_16x16x32_bf16(fAh[i], fBl[j], acc[i][j], 0, 0, 0);
            }
        cur ^= 1;
    }
    #pragma unroll
    for (int i = 0; i < 4; i++) {
        int mloc = wm*64 + i*16 + lk*4;
        #pragma unroll
        for (int j = 0; j < 4; j++) {
            int nloc = wn*64 + j*16 + lr;
            float bv = bias1[nloc];
            #pragma unroll
            for (int q = 0; q < 4; q++)
                hidS[(mloc+q)*132 + nloc] = acc[i][j][q] + bv;
        }
    }
    __syncthreads();
    for (int oi = tid; oi < 128*NT; oi += 256) {
        int m = oi / NT, j = oi - m*NT;
        const float* hr = &hidS[m*132];
        const float* wr = &w2S[j*132];
        float s = b2S[j];
        #pragma unroll 8
        for (int k = 0; k < NHID; k += 4) {
            float4 h4 = *(const float4*)(hr+k);
            float4 w4 = *(const float4*)(wr+k);
            s += h4.x*w4.x + h4.y*w4.y + h4.z*w4.z + h4.w*w4.w;
        }
        em[(size_t)(bm+m)*NT + j] = s;
    }
}

// ---------------- persistent LSTM layer (r15-exact: per-chunk flags, barrier C) --
// 3rd confirmation: block-drain barrier C + single per-chunk flag is the
// optimal release (r9/r16 per-wave variants both regressed ~+700us).
__global__ __launch_bounds__(512, 2) void k_lstm_layer(
    const float* __restrict__ zxcat,
    const float* __restrict__ Whh_f, const float* __restrict__ Whh_b,
    unsigned short* __restrict__ h_hi, unsigned short* __restrict__ h_lo,
    unsigned* __restrict__ hbf, unsigned* __restrict__ flags)
{
    int chunk = blockIdx.x;
    int dir   = blockIdx.y;
    int tid = threadIdx.x;
    int wv = tid >> 6, l = tid & 63;
    int g  = wv & 3;
    int ks = wv >> 2;
    int lr = l & 15, lk = l >> 4;
    const float* zx  = zxcat + dir*NG4;
    const float* Whh = dir ? Whh_b : Whh_f;
    unsigned* hb = hbf + (size_t)dir * (2*NB*NH);
    unsigned* flag = flags + (size_t)dir * NCHUNK * 16;

    short8v bwh[2][8], bwl[2][8];
    #pragma unroll
    for (int uh = 0; uh < 2; uh++) {
        const float* wrow = Whh + ((size_t)(g*NH + chunk*32 + uh*16 + lr))*NH + ks*256 + lk*8;
        #pragma unroll
        for (int kt = 0; kt < 8; kt++) {
            float u[8];
            *(float4*)&u[0] = *(const float4*)(wrow + kt*32);
            *(float4*)&u[4] = *(const float4*)(wrow + kt*32 + 4);
            short8v sh, sl;
            #pragma unroll
            for (int j = 0; j < 8; j++) {
                short hi = f2bf(u[j]);
                sh[j] = hi;
                sl[j] = f2bf(u[j] - bf2f(hi));
            }
            bwh[uh][kt] = sh; bwl[uh][kt] = sl;
        }
    }

    __shared__ unsigned hstage[32*516];
    __shared__ float zsh[2][4][32][33];
    float c0 = 0.f, c1 = 0.f;

    for (int t = 0; t < NS; t++) {
        int t_eff = dir ? (NS-1-t) : t;

        float pz[2][4];
        #pragma unroll
        for (int cc = 0; cc < 2; cc++) {
            int cell = tid + cc*512, b = cell >> 5, u = cell & 31;
            const float* zr = zx + ((size_t)(b*NS + t_eff))*NGS + chunk*32 + u;
            #pragma unroll
            for (int g2 = 0; g2 < 4; g2++) pz[cc][g2] = zr[g2*NH];
        }

        if (t > 0) {
            {
                const unsigned* fp = &flag[(l & 15)*16];
                unsigned v;
                do { v = ld_sc1(fp); } while (!__all((int)(v >= (unsigned)t)));
                asm volatile("" ::: "memory");
            }
            const unsigned* hp = hb + ((t-1)&1)*(NB*NH);
            unsigned sv[32];
            #pragma unroll
            for (int i = 0; i < 32; i++) sv[i] = ld_sc1(hp + i*512 + tid);
            #pragma unroll
            for (int i = 0; i < 32; i++) hstage[i*516 + tid] = sv[i];
        }
        __syncthreads();   // barrier A: stage visible

        f32x4 acc[2][2][3];
        #pragma unroll
        for (int bh = 0; bh < 2; bh++)
            #pragma unroll
            for (int uh = 0; uh < 2; uh++)
                #pragma unroll
                for (int q = 0; q < 3; q++) acc[bh][uh][q] = (f32x4){0.f,0.f,0.f,0.f};
        if (t > 0) {
            #pragma unroll
            for (int kt = 0; kt < 8; kt++) {
                short8v ah[2], al[2];
                #pragma unroll
                for (int bh = 0; bh < 2; bh++) {
                    unsigned w8[8];
                    const unsigned* sp = hstage + (bh*16+lr)*516 + ks*256 + kt*32 + lk*8;
                    *(uint4*)&w8[0] = *(const uint4*)sp;
                    *(uint4*)&w8[4] = *(const uint4*)(sp+4);
                    unpack8(w8, ah[bh], al[bh]);
                }
                #pragma unroll
                for (int bh = 0; bh < 2; bh++)
                    #pragma unroll
                    for (int uh = 0; uh < 2; uh++) {
                        acc[bh][uh][0] = __builtin_amdgcn_mfma_f32_16x16x32_bf16(ah[bh], bwh[uh][kt], acc[bh][uh][0], 0, 0, 0);
                        acc[bh][uh][1] = __builtin_amdgcn_mfma_f32_16x16x32_bf16(al[bh], bwh[uh][kt], acc[bh][uh][1], 0, 0, 0);
                        acc[bh][uh][2] = __builtin_amdgcn_mfma_f32_16x16x32_bf16(ah[bh], bwl[uh][kt], acc[bh][uh][2], 0, 0, 0);
                    }
            }
        }
        #pragma unroll
        for (int bh = 0; bh < 2; bh++)
            #pragma unroll
            for (int uh = 0; uh < 2; uh++)
                #pragma unroll
                for (int j = 0; j < 4; j++)
                    zsh[ks][g][bh*16 + lk*4 + j][uh*16 + lr] =
                        acc[bh][uh][0][j] + acc[bh][uh][1][j] + acc[bh][uh][2][j];
        __syncthreads();   // barrier B: zsh ready

        unsigned hq0 = 0, hq1 = 0;
        #pragma unroll
        for (int cc = 0; cc < 2; cc++) {
            int cell = tid + cc*512, b = cell >> 5, u = cell & 31;
            float zi = pz[cc][0] + zsh[0][0][b][u] + zsh[1][0][b][u];
            float zf = pz[cc][1] + zsh[0][1][b][u] + zsh[1][1][b][u];
            float zg = pz[cc][2] + zsh[0][2][b][u] + zsh[1][2][b][u];
            float zo = pz[cc][3] + zsh[0][3][b][u] + zsh[1][3][b][u];
            float cold = cc ? c1 : c0;
            float cn = sigmoidf_(zf)*cold + sigmoidf_(zi)*tanhf(zg);
            float hn = sigmoidf_(zo)*tanhf(cn);
            unsigned pk = packbf3(hn);
            if (cc) { c1 = cn; hq1 = pk; } else { c0 = cn; hq0 = pk; }
            st_sc1(&hb[(size_t)(t&1)*(NB*NH) + b*NH + chunk*32 + u], pk);
        }
        __syncthreads();   // barrier C: all waves' stores drained
        if (tid == 0)
            st_sc1(&flag[chunk*16], (unsigned)(t+1));
        #pragma unroll
        for (int cc = 0; cc < 2; cc++) {
            int cell = tid + cc*512, b = cell >> 5, u = cell & 31;
            unsigned pk = cc ? hq1 : hq0;
            size_t o = ((size_t)(b*NS + t_eff))*NIN1 + dir*NH + chunk*32 + u;
            h_hi[o] = (unsigned short)(pk >> 16);
            h_lo[o] = (unsigned short)(pk & 0xFFFFu);
        }
    }
}

// ---------------- fused CRF: viterbi decode + NLL forward in one pass ---------
__global__ __launch_bounds__(64) void k_crf(const float* __restrict__ em,
    const int* __restrict__ tags, const float* __restrict__ start,
    const float* __restrict__ endv, const float* __restrict__ trans,
    float* __restrict__ dec, float* __restrict__ partial)
{
    __shared__ float tr[NT][NT];
    __shared__ float vsc[NT], nsc[NT];
    __shared__ unsigned char hist[NS][NT];
    __shared__ float numsh;
    int b = blockIdx.x, tid = threadIdx.x;
    for (int i = tid; i < NT*NT; i += 64) tr[i/NT][i%NT] = trans[i];
    if (tid < NT) {
        float e0 = em[((size_t)b*NS)*NT + tid];
        vsc[tid] = start[tid] + e0;
        nsc[tid] = start[tid] + e0;
    }
    __syncthreads();
    const int* tg = tags + b*NS;
    float num = 0.f;
    for (int t = 1; t < NS; t++) {
        float nv_v = 0.f, nv_n = 0.f;
        if (tid < NT) {
            float emv = em[((size_t)b*NS + t)*NT + tid];
            float best = -1e30f; int bi = 0;
            float m = -1e30f;
            for (int i = 0; i < NT; i++) {
                float v = vsc[i] + tr[i][tid];
                if (v > best) { best = v; bi = i; }
                m = fmaxf(m, nsc[i] + tr[i][tid]);
            }
            hist[t][tid] = (unsigned char)bi;
            nv_v = best + emv;
            float s = 0.f;
            for (int i = 0; i < NT; i++) s += expf(nsc[i] + tr[i][tid] - m);
            nv_n = m + logf(s) + emv;
        } else if (tid == 32) {
            num += tr[tg[t-1]][tg[t]] + em[((size_t)b*NS + t)*NT + tg[t]];
        }
        __syncthreads();
        if (tid < NT) { vsc[tid] = nv_v; nsc[tid] = nv_n; }
        __syncthreads();
    }
    if (tid == 32) numsh = num;
    __syncthreads();
    if (tid == 0) {
        float bv = vsc[0] + endv[0]; int tag = 0;
        for (int j = 1; j < NT; j++) { float v = vsc[j] + endv[j]; if (v > bv) { bv = v; tag = j; } }
        dec[b*NS + NS-1] = (float)tag;
        for (int t = NS-1; t >= 1; t--) { tag = hist[t][tag]; dec[b*NS + t-1] = (float)tag; }
        float m = -1e30f;
        for (int j = 0; j < NT; j++) m = fmaxf(m, nsc[j] + endv[j]);
        float s = 0.f;
        for (int j = 0; j < NT; j++) s += expf(nsc[j] + endv[j] - m);
        float logZ = m + logf(s);
        float numer = start[tg[0]] + em[((size_t)b*NS)*NT + tg[0]] + numsh + endv[tg[NS-1]];
        partial[b] = -(numer - logZ);
    }
}

__global__ void k_loss_final(const float* __restrict__ partial, float* __restrict__ loss)
{
    if (threadIdx.x == 0 && blockIdx.x == 0) {
        float s = 0.f;
        for (int b = 0; b < NB; b++) s += partial[b];
        *loss = s / (float)(NB*NS);
    }
}

extern "C" void kernel_launch(void* const* d_in, const int* in_sizes, int n_in,
                              void* d_out, int out_size, void* d_ws, size_t ws_size,
                              hipStream_t stream)
{
    const int*   x_word = (const int*)d_in[0];
    const float* x_pos  = (const float*)d_in[1];
    const int*   x_char = (const int*)d_in[2];
    const float* x_enr  = (const float*)d_in[3];
    const int*   y_word = (const int*)d_in[5];
    const float* wembW  = (const float*)d_in[6];
    const float* cembW  = (const float*)d_in[7];
    const float* cnnW   = (const float*)d_in[8];
    const float* cnnb   = (const float*)d_in[9];
    const float* lin1W  = (const float*)d_in[10];
    const float* lin1b  = (const float*)d_in[11];
    const float* lin2W  = (const float*)d_in[12];
    const float* lin2b  = (const float*)d_in[13];
    const float* crf_s  = (const float*)d_in[14];
    const float* crf_e  = (const float*)d_in[15];
    const float* crf_tr = (const float*)d_in[16];
    const float* l0f_Wih = (const float*)d_in[17];
    const float* l0f_Whh = (const float*)d_in[18];
    const float* l0f_b   = (const float*)d_in[19];
    const float* l0b_Wih = (const float*)d_in[20];
    const float* l0b_Whh = (const float*)d_in[21];
    const float* l0b_b   = (const float*)d_in[22];
    const float* l1f_Wih = (const float*)d_in[23];
    const float* l1f_Whh = (const float*)d_in[24];
    const float* l1f_b   = (const float*)d_in[25];
    const float* l1b_Wih = (const float*)d_in[26];
    const float* l1b_Whh = (const float*)d_in[27];
    const float* l1b_b   = (const float*)d_in[28];

    char* wsb = (char*)d_ws;
    size_t off = 0;
    auto alloc = [&](size_t bytes) { char* p = wsb + off; off += (bytes + 255) & ~(size_t)255; return p; };
    unsigned short* xh  = (unsigned short*)alloc((size_t)NBS*NIN0P*2);
    unsigned short* xl  = (unsigned short*)alloc((size_t)NBS*NIN0P*2);
    unsigned short* whA = (unsigned short*)alloc((size_t)SWTOT*2);
    unsigned short* wlA = (unsigned short*)alloc((size_t)SWTOT*2);
    float*    zxcat = (float*)alloc((size_t)NBS*NGS*4);
    unsigned short* h0h = (unsigned short*)alloc((size_t)NBS*NIN1*2);
    unsigned short* h0l = (unsigned short*)alloc((size_t)NBS*NIN1*2);
    unsigned short* h1h = (unsigned short*)alloc((size_t)NBS*NIN1*2);
    unsigned short* h1l = (unsigned short*)alloc((size_t)NBS*NIN1*2);
    float*    partial = (float*)alloc(256);
    float*    bias0 = (float*)alloc((size_t)NGS*4);
    float*    bias1 = (float*)alloc((size_t)NGS*4);
    unsigned* hbf   = (unsigned*)alloc((size_t)2*2*NB*NH*4);
    unsigned* flags = (unsigned*)alloc((size_t)2*NCHUNK*16*4);

    unsigned short* w0h = whA;
    unsigned short* w1h = whA + 2*(size_t)SW0;
    unsigned short* wlh = whA + 2*(size_t)SW0 + 2*(size_t)SW1;
    unsigned short* w0l = wlA;
    unsigned short* w1l = wlA + 2*(size_t)SW0;
    unsigned short* wll = wlA + 2*(size_t)SW0 + 2*(size_t)SW1;

    float* em_out   = (float*)d_out;
    float* dec_out  = em_out + (size_t)NBS*NT;
    float* loss_out = dec_out + NBS;

    // 1. pack ALL weights (one dispatch)
    k_pack_all<<<(SWTOT+255)/256, 256, 0, stream>>>(l0f_Wih, l0b_Wih, l1f_Wih, l1b_Wih,
                                                    lin1W, whA, wlA);
    // cat biases
    hipMemcpyAsync(bias0,       l0f_b, NG4*4, hipMemcpyDeviceToDevice, stream);
    hipMemcpyAsync(bias0 + NG4, l0b_b, NG4*4, hipMemcpyDeviceToDevice, stream);
    hipMemcpyAsync(bias1,       l1f_b, NG4*4, hipMemcpyDeviceToDevice, stream);
    hipMemcpyAsync(bias1 + NG4, l1b_b, NG4*4, hipMemcpyDeviceToDevice, stream);
    // 2. features (hi/lo planes)
    k_features<<<NBS, 128, 0, stream>>>(x_word, x_pos, x_char, x_enr, wembW, cembW, cnnW, cnnb, xh, xl);
    // 3. layer-0 fused input projection (both dirs, N=4096)
    k_gemm_hl<<<dim3(NBS/128, NGS/128), 256, 0, stream>>>(xh, xl, w0h, w0l, bias0, zxcat, NBS, NGS, NIN0P);
    // 4. layer-0 recurrence
    hipMemsetAsync(flags, 0, (size_t)2*NCHUNK*16*4, stream);
    k_lstm_layer<<<dim3(NCHUNK, 2), 512, 0, stream>>>(zxcat, l0f_Whh, l0b_Whh, h0h, h0l, hbf, flags);
    // 5. layer-1 fused input projection
    k_gemm_hl<<<dim3(NBS/128, NGS/128), 256, 0, stream>>>(h0h, h0l, w1h, w1l, bias1, zxcat, NBS, NGS, NIN1);
    // 6. layer-1 recurrence
    hipMemsetAsync(flags, 0, (size_t)2*NCHUNK*16*4, stream);
    k_lstm_layer<<<dim3(NCHUNK, 2), 512, 0, stream>>>(zxcat, l1f_Whh, l1b_Whh, h1h, h1l, hbf, flags);
    // 7. head GEMM fused with lin2 -> em
    k_gemm_head<<<NBS/128, 256, 0, stream>>>(h1h, h1l, wlh, wll, lin1b, lin2W, lin2b, em_out, NIN1);
    // 8. CRF (fused viterbi + nll)
    k_crf<<<NB, 64, 0, stream>>>(em_out, y_word, crf_s, crf_e, crf_tr, dec_out, partial);
    k_loss_final<<<1, 64, 0, stream>>>(partial, loss_out);
}